// Round 16
// baseline (151.920 us; speedup 1.0000x reference)
//
#include <hip/hip_runtime.h>

// 3-layer GCN on MI355X.
// Structure: per-node normalization factored (aggregate pre-scaled values),
// adjacency = fixed-capacity buckets, no count/scan:
//   memset(cursor) -> k_fill (cursor ends = in-degree)
//   -> k_gemm12 (agg1 + L1 + L2 linear -> t2s) -> k_agg2 -> k_agg3.
// R16: gemm12 = MB=32, 4 nodes x 4 cols/thread (cuts phase-B wave-LDS-instr
// per node 33% — w2 re-issue redundancy 8x->4x) + R15 register prefetch +
// balanced stage-0 + b128 phase-A reads (AP=12). agg2/agg3/fill = R15 frozen.
// Lessons: R3 atomic scatter=186us; R4 grid.sync~100us; R7/R13 global W2 in
// k-loop = latency-bound — W2 must be LDS-staged; R14 128t blocks = 2 waves
// can't hide barriers (71us); R9 conflated r4c4 with unbalanced stage-0;
// macro params must not be named 'w' ('.w' token collision).

constexpr int NN  = 20000;  // nodes
constexpr int NE  = 320000; // edges
constexpr int F0  = 10;     // input feats
constexpr int F1  = 256;    // layer1 out
constexpr int F2  = 128;    // layer2 out
constexpr int MB  = 32;     // nodes per gemm12 tile
constexpr int CAP = 64;     // bucket capacity (max in-deg ~36, P(>=64)~2e-18)
constexpr int AP  = 12;     // alds padded row stride (16B-aligned rows)

// ---------- adjacency fill ----------

__global__ void k_fill(const int* __restrict__ src, const int* __restrict__ dst,
                       int* cursor, int* __restrict__ col) {
  int e = blockIdx.x * 256 + threadIdx.x;
  if (e >= NE) return;
  const int d = dst[e], s = src[e];
  const int pos = atomicAdd(&cursor[d], 1) & (CAP - 1);
  col[d * CAP + pos] = s;
}

// ---------- fused: a1 (LDS) -> h1 = relu(a1 W1 + b1) (LDS) -> t2s = dinv*(h1 W2)

__global__ __launch_bounds__(256) void k_gemm12(
    const float* __restrict__ x, const int* __restrict__ cursor,
    const int* __restrict__ col, const float* __restrict__ W1,
    const float* __restrict__ b1, const float* __restrict__ W2,
    float* __restrict__ t2s) {
  __shared__ float alds[MB * AP];     // 1.5 KB, stride-12 rows
  __shared__ float h1[MB][F1 + 4];    // 33.3 KB
  __shared__ float w2lds[32 * F2];    // 16 KB, one 32-row chunk of W2
  const int tid = threadIdx.x;
  const int n0 = blockIdx.x * MB;
  // stage 0 (balanced): pass 1 = 256 threads cover 32 nodes x f=0..7;
  // pass 2 = 64 threads cover f=8,9.
  {
    const int m = tid >> 3;
    const int f = tid & 7;
    const int n = n0 + m;
    const int deg = cursor[n];
    const int base = n * CAP;
    const float di = rsqrtf((float)(deg + 1));
    float acc = x[n * F0 + f] * di;  // self-loop
    int k = 0;
    for (; k + 3 < deg; k += 4) {
      const int s0 = col[base + k],     s1 = col[base + k + 1];
      const int s2 = col[base + k + 2], s3 = col[base + k + 3];
      const float d0 = rsqrtf((float)(cursor[s0] + 1));
      const float d1 = rsqrtf((float)(cursor[s1] + 1));
      const float d2 = rsqrtf((float)(cursor[s2] + 1));
      const float d3 = rsqrtf((float)(cursor[s3] + 1));
      acc += x[s0 * F0 + f] * d0 + x[s1 * F0 + f] * d1 +
             x[s2 * F0 + f] * d2 + x[s3 * F0 + f] * d3;
    }
    for (; k < deg; ++k) {
      const int s = col[base + k];
      acc += x[s * F0 + f] * rsqrtf((float)(cursor[s] + 1));
    }
    alds[m * AP + f] = di * acc;
  }
  if (tid < 64) {  // pass 2: f = 8, 9
    const int m = tid >> 1;
    const int f = 8 + (tid & 1);
    const int n = n0 + m;
    const int deg = cursor[n];
    const int base = n * CAP;
    const float di = rsqrtf((float)(deg + 1));
    float acc = x[n * F0 + f] * di;
    int k = 0;
    for (; k + 3 < deg; k += 4) {
      const int s0 = col[base + k],     s1 = col[base + k + 1];
      const int s2 = col[base + k + 2], s3 = col[base + k + 3];
      const float d0 = rsqrtf((float)(cursor[s0] + 1));
      const float d1 = rsqrtf((float)(cursor[s1] + 1));
      const float d2 = rsqrtf((float)(cursor[s2] + 1));
      const float d3 = rsqrtf((float)(cursor[s3] + 1));
      acc += x[s0 * F0 + f] * d0 + x[s1 * F0 + f] * d1 +
             x[s2 * F0 + f] * d2 + x[s3 * F0 + f] * d3;
    }
    for (; k < deg; ++k) {
      const int s = col[base + k];
      acc += x[s * F0 + f] * rsqrtf((float)(cursor[s] + 1));
    }
    alds[m * AP + f] = di * acc;
  }
  // prefetch W2 chunk 0 while waiting at the barrier
  float4 pf0 = *((const float4*)W2 + tid);
  float4 pf1 = *((const float4*)W2 + tid + 256);
  float4 pf2 = *((const float4*)W2 + tid + 512);
  float4 pf3 = *((const float4*)W2 + tid + 768);
  __syncthreads();
  {  // phase A: thread = layer-1 channel c; alds rows read as 3x b128
    const int c = tid;
    float w1r[F0];
#pragma unroll
    for (int k = 0; k < F0; ++k) w1r[k] = W1[k * F1 + c];
    const float bb = b1[c];
#pragma unroll
    for (int m = 0; m < MB; ++m) {
      const float4 r0 = *(const float4*)&alds[m * AP + 0];
      const float4 r1 = *(const float4*)&alds[m * AP + 4];
      const float4 r2 = *(const float4*)&alds[m * AP + 8];  // .x,.y valid
      float acc = bb;
      acc += r0.x * w1r[0] + r0.y * w1r[1] + r0.z * w1r[2] + r0.w * w1r[3];
      acc += r1.x * w1r[4] + r1.y * w1r[5] + r1.z * w1r[6] + r1.w * w1r[7];
      acc += r2.x * w1r[8] + r2.y * w1r[9];
      h1[m][c] = fmaxf(acc, 0.f);
    }
  }
  // phase B: 4 nodes x 4 cols per thread; W2 LDS-chunked + register prefetch.
  const int cg_ = tid & 31;       // 32 col-quads
  const int m0 = (tid >> 5) * 4;  // 8 groups of 4 nodes = 32
  float a[4][4] = {{0.f, 0.f, 0.f, 0.f}, {0.f, 0.f, 0.f, 0.f},
                   {0.f, 0.f, 0.f, 0.f}, {0.f, 0.f, 0.f, 0.f}};
#define FMA1(i, hv, vw4)                                            \
  a[i][0] += (hv) * (vw4).x; a[i][1] += (hv) * (vw4).y;             \
  a[i][2] += (hv) * (vw4).z; a[i][3] += (hv) * (vw4).w;
  for (int kc = 0; kc < F1 / 32; ++kc) {
    __syncthreads();  // prev chunk consumed (kc=0: h1 written by phase A)
    {  // commit prefetched chunk to LDS
      float4* ldst = (float4*)w2lds;
      ldst[tid] = pf0;
      ldst[tid + 256] = pf1;
      ldst[tid + 512] = pf2;
      ldst[tid + 768] = pf3;
    }
    __syncthreads();
    if (kc + 1 < F1 / 32) {  // issue next-chunk loads; in flight during compute
      const float4* gnext = (const float4*)(W2 + (kc + 1) * 32 * F2);
      pf0 = gnext[tid];
      pf1 = gnext[tid + 256];
      pf2 = gnext[tid + 512];
      pf3 = gnext[tid + 768];
    }
#pragma unroll
    for (int kk = 0; kk < 32; kk += 4) {
      const int k = kc * 32 + kk;
      const float4 w0 = *(const float4*)&w2lds[(kk + 0) * F2 + cg_ * 4];
      const float4 w1v = *(const float4*)&w2lds[(kk + 1) * F2 + cg_ * 4];
      const float4 w2v = *(const float4*)&w2lds[(kk + 2) * F2 + cg_ * 4];
      const float4 w3v = *(const float4*)&w2lds[(kk + 3) * F2 + cg_ * 4];
      const float4 h0 = *(const float4*)&h1[m0 + 0][k];
      const float4 hA = *(const float4*)&h1[m0 + 1][k];
      const float4 hB = *(const float4*)&h1[m0 + 2][k];
      const float4 hC = *(const float4*)&h1[m0 + 3][k];
      FMA1(0, h0.x, w0); FMA1(0, h0.y, w1v); FMA1(0, h0.z, w2v); FMA1(0, h0.w, w3v);
      FMA1(1, hA.x, w0); FMA1(1, hA.y, w1v); FMA1(1, hA.z, w2v); FMA1(1, hA.w, w3v);
      FMA1(2, hB.x, w0); FMA1(2, hB.y, w1v); FMA1(2, hB.z, w2v); FMA1(2, hB.w, w3v);
      FMA1(3, hC.x, w0); FMA1(3, hC.y, w1v); FMA1(3, hC.z, w2v); FMA1(3, hC.w, w3v);
    }
  }
#undef FMA1
#pragma unroll
  for (int i = 0; i < 4; ++i) {
    const int n = n0 + m0 + i;
    const float dd = rsqrtf((float)(cursor[n] + 1));
    *(float4*)&t2s[(size_t)n * F2 + cg_ * 4] =
        make_float4(a[i][0] * dd, a[i][1] * dd, a[i][2] * dd, a[i][3] * dd);
  }
}

// ---------- layer-2 aggregation + layer-3 transform (R15 frozen) ----------

__global__ __launch_bounds__(256) void k_agg2(
    const float* __restrict__ t2s, const int* __restrict__ cursor,
    const int* __restrict__ col, const float* __restrict__ b2,
    const float* __restrict__ W3, float* __restrict__ t3s) {
  const int wave = (blockIdx.x * 256 + threadIdx.x) >> 6;
  const int lane = threadIdx.x & 63;
  const int half = lane >> 5;
  const int li   = lane & 31;
  const int n    = wave * 2 + half;
  if (n >= NN) return;
  const int deg = cursor[n];
  const int base = n * CAP;
  const int fx = li * 4;
  const float4 vs = *(const float4*)&t2s[(size_t)n * F2 + fx];
  float a0 = vs.x, a1 = vs.y, a2 = vs.z, a3 = vs.w;
  int k = 0;
  for (; k + 7 < deg; k += 8) {
    const int s0 = col[base + k],     s1 = col[base + k + 1];
    const int s2 = col[base + k + 2], s3 = col[base + k + 3];
    const int s4 = col[base + k + 4], s5 = col[base + k + 5];
    const int s6 = col[base + k + 6], s7 = col[base + k + 7];
    const float4 v0 = *(const float4*)&t2s[(size_t)s0 * F2 + fx];
    const float4 v1 = *(const float4*)&t2s[(size_t)s1 * F2 + fx];
    const float4 v2 = *(const float4*)&t2s[(size_t)s2 * F2 + fx];
    const float4 v3 = *(const float4*)&t2s[(size_t)s3 * F2 + fx];
    const float4 v4 = *(const float4*)&t2s[(size_t)s4 * F2 + fx];
    const float4 v5 = *(const float4*)&t2s[(size_t)s5 * F2 + fx];
    const float4 v6 = *(const float4*)&t2s[(size_t)s6 * F2 + fx];
    const float4 v7 = *(const float4*)&t2s[(size_t)s7 * F2 + fx];
    a0 += ((v0.x + v1.x) + (v2.x + v3.x)) + ((v4.x + v5.x) + (v6.x + v7.x));
    a1 += ((v0.y + v1.y) + (v2.y + v3.y)) + ((v4.y + v5.y) + (v6.y + v7.y));
    a2 += ((v0.z + v1.z) + (v2.z + v3.z)) + ((v4.z + v5.z) + (v6.z + v7.z));
    a3 += ((v0.w + v1.w) + (v2.w + v3.w)) + ((v4.w + v5.w) + (v6.w + v7.w));
  }
  for (; k + 3 < deg; k += 4) {
    const int s0 = col[base + k],     s1 = col[base + k + 1];
    const int s2 = col[base + k + 2], s3 = col[base + k + 3];
    const float4 v0 = *(const float4*)&t2s[(size_t)s0 * F2 + fx];
    const float4 v1 = *(const float4*)&t2s[(size_t)s1 * F2 + fx];
    const float4 v2 = *(const float4*)&t2s[(size_t)s2 * F2 + fx];
    const float4 v3 = *(const float4*)&t2s[(size_t)s3 * F2 + fx];
    a0 += (v0.x + v1.x) + (v2.x + v3.x);
    a1 += (v0.y + v1.y) + (v2.y + v3.y);
    a2 += (v0.z + v1.z) + (v2.z + v3.z);
    a3 += (v0.w + v1.w) + (v2.w + v3.w);
  }
  for (; k < deg; ++k) {
    const float4 v = *(const float4*)&t2s[(size_t)col[base + k] * F2 + fx];
    a0 += v.x; a1 += v.y; a2 += v.z; a3 += v.w;
  }
  const float di = rsqrtf((float)(deg + 1));
  const float4 bb = *(const float4*)&b2[fx];
  const float4 w3 = *(const float4*)&W3[fx];
  const float h0 = fmaxf(di * a0 + bb.x, 0.f);
  const float h1 = fmaxf(di * a1 + bb.y, 0.f);
  const float h2 = fmaxf(di * a2 + bb.z, 0.f);
  const float h3 = fmaxf(di * a3 + bb.w, 0.f);
  float p = (h0 * w3.x + h1 * w3.y) + (h2 * w3.z + h3 * w3.w);
#pragma unroll
  for (int off = 16; off > 0; off >>= 1) p += __shfl_down(p, off);
  if (li == 0) t3s[n] = di * p;
}

// ---------- layer-3 aggregation (R15 frozen) ----------

__global__ void k_agg3(const float* __restrict__ t3s, const int* __restrict__ cursor,
                       const int* __restrict__ col, const float* __restrict__ b3,
                       float* __restrict__ out) {
  int n = blockIdx.x * 256 + threadIdx.x;
  if (n >= NN) return;
  const int deg = cursor[n];
  const int base = n * CAP;
  float acc = t3s[n];
  int k = 0;
  for (; k + 7 < deg; k += 8)
    acc += ((t3s[col[base + k]] + t3s[col[base + k + 1]]) +
            (t3s[col[base + k + 2]] + t3s[col[base + k + 3]])) +
           ((t3s[col[base + k + 4]] + t3s[col[base + k + 5]]) +
            (t3s[col[base + k + 6]] + t3s[col[base + k + 7]]));
  for (; k < deg; ++k) acc += t3s[col[base + k]];
  out[n] = rsqrtf((float)(deg + 1)) * acc + b3[0];
}

extern "C" void kernel_launch(void* const* d_in, const int* in_sizes, int n_in,
                              void* d_out, int out_size, void* d_ws, size_t ws_size,
                              hipStream_t stream) {
  const float* x = (const float*)d_in[0];
  const int* ei = (const int*)d_in[1];
  const int* srcv = ei;       // edge_index[0]
  const int* dstv = ei + NE;  // edge_index[1]
  const float* W1 = (const float*)d_in[2];
  const float* b1 = (const float*)d_in[3];
  const float* W2 = (const float*)d_in[4];
  const float* b2 = (const float*)d_in[5];
  const float* W3 = (const float*)d_in[6];
  const float* b3 = (const float*)d_in[7];
  float* out = (float*)d_out;

  char* w = (char*)d_ws;
  auto alloc = [&](size_t bytes) -> void* {
    void* p = (void*)w;
    w += (bytes + 255) & ~(size_t)255;
    return p;
  };
  int*   cursor = (int*)  alloc(NN * 4);
  int*   col    = (int*)  alloc((size_t)NN * CAP * 4);
  float* t2s    = (float*)alloc((size_t)NN * F2 * 4);
  float* t3s    = (float*)alloc(NN * 4);

  (void)hipMemsetAsync(cursor, 0, NN * 4, stream);
  k_fill<<<(NE + 255) / 256, 256, 0, stream>>>(srcv, dstv, cursor, col);
  k_gemm12<<<NN / MB, 256, 0, stream>>>(x, cursor, col, W1, b1, W2, t2s);
  k_agg2<<<NN / 8, 256, 0, stream>>>(t2s, cursor, col, b2, W3, t3s);
  k_agg3<<<(NN + 255) / 256, 256, 0, stream>>>(t3s, cursor, col, b3, out);
}

// Round 17
// 149.177 us; speedup vs baseline: 1.0184x; 1.0184x over previous
//
#include <hip/hip_runtime.h>

// 3-layer GCN on MI355X — FINAL (R15-exact restore; measured best 149.8us).
// Structure: per-node normalization factored (aggregate pre-scaled values),
// adjacency = fixed-capacity buckets, no count/scan:
//   memset(cursor) -> k_fill (cursor ends = in-degree)
//   -> k_gemm12 (agg1 + L1 + L2 linear -> t2s) -> k_agg2 -> k_agg3.
// gemm12: MB=16 (1250 blocks), W2 LDS-staged in 32-row chunks with REGISTER
// prefetch of chunk kc+1 during chunk-kc compute; float4 h1/w2 reads.
// agg2: 2 nodes/wave (half-wave x float4), 8 gathers in flight.
// Lessons (all measured): R3 multi-float atomic scatter=186us; R4 cooperative
// grid.sync~100us each; R7/R13 W2 streamed from global in k-loop =
// latency-bound (~51us) regardless of redundancy — W2 must be LDS-staged;
// R9/R11/R16 MB=32 always loses ~2-6us to MB=16 (625-block grid tail);
// R14 128t blocks = 2 waves can't hide chunk barriers (71us, VGPR 132);
// R10 wave-count bug (256t block = 4 waves); macro params must not be named
// 'w' (preprocessor substitutes into '.w' member tokens).

constexpr int NN  = 20000;  // nodes
constexpr int NE  = 320000; // edges
constexpr int F0  = 10;     // input feats
constexpr int F1  = 256;    // layer1 out
constexpr int F2  = 128;    // layer2 out
constexpr int MB  = 16;     // nodes per gemm12 tile
constexpr int CAP = 64;     // bucket capacity (max in-deg ~36, P(>=64)~2e-18)

// ---------- adjacency fill ----------

__global__ void k_fill(const int* __restrict__ src, const int* __restrict__ dst,
                       int* cursor, int* __restrict__ col) {
  int e = blockIdx.x * 256 + threadIdx.x;
  if (e >= NE) return;
  const int d = dst[e], s = src[e];
  const int pos = atomicAdd(&cursor[d], 1) & (CAP - 1);
  col[d * CAP + pos] = s;
}

// ---------- fused: a1 (LDS) -> h1 = relu(a1 W1 + b1) (LDS) -> t2s = dinv*(h1 W2)

__global__ __launch_bounds__(256) void k_gemm12(
    const float* __restrict__ x, const int* __restrict__ cursor,
    const int* __restrict__ col, const float* __restrict__ W1,
    const float* __restrict__ b1, const float* __restrict__ W2,
    float* __restrict__ t2s) {
  __shared__ float alds[MB * F0];     // 640 B
  __shared__ float h1[MB][F1 + 4];    // 16.6 KB, k-contiguous per node
  __shared__ float w2lds[32 * F2];    // 16 KB, one 32-row chunk of W2
  const int tid = threadIdx.x;
  const int n0 = blockIdx.x * MB;
  // stage 0: layer-1 aggregation into LDS; dinv on the fly from cursor
  {
    const int m = tid >> 4;
    const int f = tid & 15;
    if (f < F0) {
      const int n = n0 + m;
      const int deg = cursor[n];
      const int base = n * CAP;
      const float di = rsqrtf((float)(deg + 1));
      float acc = x[n * F0 + f] * di;  // self-loop
      int k = 0;
      for (; k + 3 < deg; k += 4) {
        const int s0 = col[base + k],     s1 = col[base + k + 1];
        const int s2 = col[base + k + 2], s3 = col[base + k + 3];
        const float d0 = rsqrtf((float)(cursor[s0] + 1));
        const float d1 = rsqrtf((float)(cursor[s1] + 1));
        const float d2 = rsqrtf((float)(cursor[s2] + 1));
        const float d3 = rsqrtf((float)(cursor[s3] + 1));
        acc += x[s0 * F0 + f] * d0 + x[s1 * F0 + f] * d1 +
               x[s2 * F0 + f] * d2 + x[s3 * F0 + f] * d3;
      }
      for (; k < deg; ++k) {
        const int s = col[base + k];
        acc += x[s * F0 + f] * rsqrtf((float)(cursor[s] + 1));
      }
      alds[m * F0 + f] = di * acc;
    }
  }
  // prefetch W2 chunk 0 while waiting at the barrier
  float4 pf0 = *((const float4*)W2 + tid);
  float4 pf1 = *((const float4*)W2 + tid + 256);
  float4 pf2 = *((const float4*)W2 + tid + 512);
  float4 pf3 = *((const float4*)W2 + tid + 768);
  __syncthreads();
  {  // phase A: thread = layer-1 channel c; h1[m][c] stride-1 in c
    const int c = tid;
    float w1r[F0];
#pragma unroll
    for (int k = 0; k < F0; ++k) w1r[k] = W1[k * F1 + c];
    const float bb = b1[c];
#pragma unroll
    for (int m = 0; m < MB; ++m) {
      float acc = bb;
#pragma unroll
      for (int k = 0; k < F0; ++k) acc += alds[m * F0 + k] * w1r[k];
      h1[m][c] = fmaxf(acc, 0.f);
    }
  }
  // phase B: 2 nodes x 4 cols per thread; W2 LDS-staged in 32-row chunks
  // with REGISTER PREFETCH of chunk kc+1 during chunk-kc compute.
  const int cg_ = tid & 31;
  const int m0 = (tid >> 5) * 2;
  float a00 = 0.f, a01 = 0.f, a02 = 0.f, a03 = 0.f;
  float a10 = 0.f, a11 = 0.f, a12 = 0.f, a13 = 0.f;
#define FMA4(av, bv, vw)                                            \
  a00 += (av) * (vw).x; a01 += (av) * (vw).y;                       \
  a02 += (av) * (vw).z; a03 += (av) * (vw).w;                       \
  a10 += (bv) * (vw).x; a11 += (bv) * (vw).y;                       \
  a12 += (bv) * (vw).z; a13 += (bv) * (vw).w;
  for (int kc = 0; kc < F1 / 32; ++kc) {
    __syncthreads();  // prev chunk consumed (kc=0: h1 written by phase A)
    {  // commit prefetched chunk to LDS
      float4* ldst = (float4*)w2lds;
      ldst[tid] = pf0;
      ldst[tid + 256] = pf1;
      ldst[tid + 512] = pf2;
      ldst[tid + 768] = pf3;
    }
    __syncthreads();
    if (kc + 1 < F1 / 32) {  // issue next-chunk loads; in flight during compute
      const float4* gnext = (const float4*)(W2 + (kc + 1) * 32 * F2);
      pf0 = gnext[tid];
      pf1 = gnext[tid + 256];
      pf2 = gnext[tid + 512];
      pf3 = gnext[tid + 768];
    }
#pragma unroll
    for (int kk = 0; kk < 32; kk += 4) {
      const int k = kc * 32 + kk;
      const float4 ha = *(const float4*)&h1[m0][k];
      const float4 hb = *(const float4*)&h1[m0 + 1][k];
      const float4 w0 = *(const float4*)&w2lds[(kk + 0) * F2 + cg_ * 4];
      const float4 w1v = *(const float4*)&w2lds[(kk + 1) * F2 + cg_ * 4];
      const float4 w2v = *(const float4*)&w2lds[(kk + 2) * F2 + cg_ * 4];
      const float4 w3v = *(const float4*)&w2lds[(kk + 3) * F2 + cg_ * 4];
      FMA4(ha.x, hb.x, w0);
      FMA4(ha.y, hb.y, w1v);
      FMA4(ha.z, hb.z, w2v);
      FMA4(ha.w, hb.w, w3v);
    }
  }
#undef FMA4
  const float d0 = rsqrtf((float)(cursor[n0 + m0] + 1));
  const float d1 = rsqrtf((float)(cursor[n0 + m0 + 1] + 1));
  *(float4*)&t2s[(size_t)(n0 + m0) * F2 + cg_ * 4] =
      make_float4(a00 * d0, a01 * d0, a02 * d0, a03 * d0);
  *(float4*)&t2s[(size_t)(n0 + m0 + 1) * F2 + cg_ * 4] =
      make_float4(a10 * d1, a11 * d1, a12 * d1, a13 * d1);
}

// ---------- layer-2 aggregation + layer-3 transform ----------
// 2 nodes per wave: half-wave (32 lanes) per node, float4 per lane (512B/row);
// 8 gathers in flight (deg~16 -> mostly 2 batches).

__global__ __launch_bounds__(256) void k_agg2(
    const float* __restrict__ t2s, const int* __restrict__ cursor,
    const int* __restrict__ col, const float* __restrict__ b2,
    const float* __restrict__ W3, float* __restrict__ t3s) {
  const int wave = (blockIdx.x * 256 + threadIdx.x) >> 6;
  const int lane = threadIdx.x & 63;
  const int half = lane >> 5;        // 0 or 1
  const int li   = lane & 31;
  const int n    = wave * 2 + half;  // 2500 blocks cover 20000 exactly
  if (n >= NN) return;
  const int deg = cursor[n];
  const int base = n * CAP;
  const int fx = li * 4;
  const float4 vs = *(const float4*)&t2s[(size_t)n * F2 + fx];
  float a0 = vs.x, a1 = vs.y, a2 = vs.z, a3 = vs.w;
  int k = 0;
  for (; k + 7 < deg; k += 8) {  // 8 coalesced 512B gathers in flight
    const int s0 = col[base + k],     s1 = col[base + k + 1];
    const int s2 = col[base + k + 2], s3 = col[base + k + 3];
    const int s4 = col[base + k + 4], s5 = col[base + k + 5];
    const int s6 = col[base + k + 6], s7 = col[base + k + 7];
    const float4 v0 = *(const float4*)&t2s[(size_t)s0 * F2 + fx];
    const float4 v1 = *(const float4*)&t2s[(size_t)s1 * F2 + fx];
    const float4 v2 = *(const float4*)&t2s[(size_t)s2 * F2 + fx];
    const float4 v3 = *(const float4*)&t2s[(size_t)s3 * F2 + fx];
    const float4 v4 = *(const float4*)&t2s[(size_t)s4 * F2 + fx];
    const float4 v5 = *(const float4*)&t2s[(size_t)s5 * F2 + fx];
    const float4 v6 = *(const float4*)&t2s[(size_t)s6 * F2 + fx];
    const float4 v7 = *(const float4*)&t2s[(size_t)s7 * F2 + fx];
    a0 += ((v0.x + v1.x) + (v2.x + v3.x)) + ((v4.x + v5.x) + (v6.x + v7.x));
    a1 += ((v0.y + v1.y) + (v2.y + v3.y)) + ((v4.y + v5.y) + (v6.y + v7.y));
    a2 += ((v0.z + v1.z) + (v2.z + v3.z)) + ((v4.z + v5.z) + (v6.z + v7.z));
    a3 += ((v0.w + v1.w) + (v2.w + v3.w)) + ((v4.w + v5.w) + (v6.w + v7.w));
  }
  for (; k + 3 < deg; k += 4) {
    const int s0 = col[base + k],     s1 = col[base + k + 1];
    const int s2 = col[base + k + 2], s3 = col[base + k + 3];
    const float4 v0 = *(const float4*)&t2s[(size_t)s0 * F2 + fx];
    const float4 v1 = *(const float4*)&t2s[(size_t)s1 * F2 + fx];
    const float4 v2 = *(const float4*)&t2s[(size_t)s2 * F2 + fx];
    const float4 v3 = *(const float4*)&t2s[(size_t)s3 * F2 + fx];
    a0 += (v0.x + v1.x) + (v2.x + v3.x);
    a1 += (v0.y + v1.y) + (v2.y + v3.y);
    a2 += (v0.z + v1.z) + (v2.z + v3.z);
    a3 += (v0.w + v1.w) + (v2.w + v3.w);
  }
  for (; k < deg; ++k) {
    const float4 v = *(const float4*)&t2s[(size_t)col[base + k] * F2 + fx];
    a0 += v.x; a1 += v.y; a2 += v.z; a3 += v.w;
  }
  const float di = rsqrtf((float)(deg + 1));
  const float4 bb = *(const float4*)&b2[fx];
  const float4 w3 = *(const float4*)&W3[fx];
  const float h0 = fmaxf(di * a0 + bb.x, 0.f);
  const float h1 = fmaxf(di * a1 + bb.y, 0.f);
  const float h2 = fmaxf(di * a2 + bb.z, 0.f);
  const float h3 = fmaxf(di * a3 + bb.w, 0.f);
  float p = (h0 * w3.x + h1 * w3.y) + (h2 * w3.z + h3 * w3.w);
#pragma unroll
  for (int off = 16; off > 0; off >>= 1) p += __shfl_down(p, off);  // within half
  if (li == 0) t3s[n] = di * p;
}

// ---------- layer-3 aggregation ----------

__global__ void k_agg3(const float* __restrict__ t3s, const int* __restrict__ cursor,
                       const int* __restrict__ col, const float* __restrict__ b3,
                       float* __restrict__ out) {
  int n = blockIdx.x * 256 + threadIdx.x;
  if (n >= NN) return;
  const int deg = cursor[n];
  const int base = n * CAP;
  float acc = t3s[n];
  int k = 0;
  for (; k + 7 < deg; k += 8)
    acc += ((t3s[col[base + k]] + t3s[col[base + k + 1]]) +
            (t3s[col[base + k + 2]] + t3s[col[base + k + 3]])) +
           ((t3s[col[base + k + 4]] + t3s[col[base + k + 5]]) +
            (t3s[col[base + k + 6]] + t3s[col[base + k + 7]]));
  for (; k < deg; ++k) acc += t3s[col[base + k]];
  out[n] = rsqrtf((float)(deg + 1)) * acc + b3[0];
}

extern "C" void kernel_launch(void* const* d_in, const int* in_sizes, int n_in,
                              void* d_out, int out_size, void* d_ws, size_t ws_size,
                              hipStream_t stream) {
  const float* x = (const float*)d_in[0];
  const int* ei = (const int*)d_in[1];
  const int* srcv = ei;       // edge_index[0]
  const int* dstv = ei + NE;  // edge_index[1]
  const float* W1 = (const float*)d_in[2];
  const float* b1 = (const float*)d_in[3];
  const float* W2 = (const float*)d_in[4];
  const float* b2 = (const float*)d_in[5];
  const float* W3 = (const float*)d_in[6];
  const float* b3 = (const float*)d_in[7];
  float* out = (float*)d_out;

  char* w = (char*)d_ws;
  auto alloc = [&](size_t bytes) -> void* {
    void* p = (void*)w;
    w += (bytes + 255) & ~(size_t)255;
    return p;
  };
  int*   cursor = (int*)  alloc(NN * 4);
  int*   col    = (int*)  alloc((size_t)NN * CAP * 4);
  float* t2s    = (float*)alloc((size_t)NN * F2 * 4);
  float* t3s    = (float*)alloc(NN * 4);

  (void)hipMemsetAsync(cursor, 0, NN * 4, stream);
  k_fill<<<(NE + 255) / 256, 256, 0, stream>>>(srcv, dstv, cursor, col);
  k_gemm12<<<NN / MB, 256, 0, stream>>>(x, cursor, col, W1, b1, W2, t2s);
  k_agg2<<<NN / 8, 256, 0, stream>>>(t2s, cursor, col, b2, W3, t3s);
  k_agg3<<<(NN + 255) / 256, 256, 0, stream>>>(t3s, cursor, col, b3, out);
}